// Round 1
// baseline (261.415 us; speedup 1.0000x reference)
//
#include <hip/hip_runtime.h>
#include <hip/hip_fp16.h>

// TwoDimensionalSSM via direct 2D recurrence. Round 7: SGPR-param restructure.
// R6 counters: VALUBusy 85%, MfmaUtil 0, HBM 7% -> pure VALU-issue-bound at
// ~22k VALU insts/wave, but static count of the loop is only ~13-14k. Theory:
// the gap is register-pressure rematerialization (2x 28-float DirP + states +
// temps ~= 90 live values vs 72 VGPRs). Fix: remap the block's 8 images so
// each wave's two half-images are 64 apart in m -> share h = m & 63 -> all
// h-dependent SSM params are wave-uniform -> pin them to SGPRs via
// readfirstlane (VOP3 fma takes 1 SGPR source; every fma here uses exactly
// one param). Per-lane values (w, a2z, ab, om) stay in VGPRs.
// Scan math, DPP controls, LDS swizzle, pass structure: identical to R6.

#define NPB 8            // images per block (one per 32-lane half, 2/wave)
#define THREADS 256
#define M_TOT 16384      // B*E
#define SCALE 0.70710678118654752f  // sqrt(1/N), N=2

template<int CTRL, int ROW_MASK, bool BC>
__device__ __forceinline__ float dppf(float v) {
    return __int_as_float(__builtin_amdgcn_update_dpp(
        0, __float_as_int(v), CTRL, ROW_MASK, 0xF, BC));
}

__device__ __forceinline__ float sigm(float v) { return 1.0f / (1.0f + __expf(-v)); }

// force a wave-uniform value into an SGPR
__device__ __forceinline__ float rfl(float v) {
    return __int_as_float(__builtin_amdgcn_readfirstlane(__float_as_int(v)));
}

// forward inclusive scan over each 32-lane half: out[j] = sum_{q<=j} a^(j-q) in[q]
__device__ __forceinline__ float scanF(float v, float a, float p2, float p4,
                                       float p8, float w) {
    v = fmaf(a,  dppf<0x111, 0xF, true >(v), v);  // row_shr:1
    v = fmaf(p2, dppf<0x112, 0xF, true >(v), v);  // row_shr:2
    v = fmaf(p4, dppf<0x114, 0xF, true >(v), v);  // row_shr:4
    v = fmaf(p8, dppf<0x118, 0xF, true >(v), v);  // row_shr:8
    v = fmaf(w,  dppf<0x142, 0xA, false>(v), v);  // row_bcast15 -> rows 1,3
    return v;
}

// reverse inclusive scan over each 32-lane half: out[j] = sum_{q>=j} a^(q-j) in[q]
__device__ __forceinline__ float scanR(float v, float a, float p2, float p4,
                                       float p8, float w) {
    v = fmaf(a,  dppf<0x101, 0xF, true>(v), v);   // row_shl:1
    v = fmaf(p2, dppf<0x102, 0xF, true>(v), v);   // row_shl:2
    v = fmaf(p4, dppf<0x104, 0xF, true>(v), v);   // row_shl:4
    v = fmaf(p8, dppf<0x108, 0xF, true>(v), v);   // row_shl:8
    // bit-mode ds_swizzle 0x0200: src = lane16 of each 32-half
    float b = __int_as_float(__builtin_amdgcn_ds_swizzle(__float_as_int(v), 0x0200));
    v = fmaf(w, b, v);
    return v;
}

struct DirP {
    // wave-uniform -> SGPR (via rfl in dir_init)
    float a1_0, a1_1, p2_0, p2_1, p4_0, p4_1, p8_0, p8_1;
    float a3_0, a3_1, a4_0, a4_1;
    float b1_0, b1_1, b2_0, b2_1, a3b1_0, a3b1_1;
    float c1s0, c1s1, c2s0, c2s1, k00;
    // per-lane -> VGPR
    float w_0, w_1, a2z0, a2z1, ab0, ab1;
};

template<bool REV>
__device__ __forceinline__ void dir_init(DirP& P, int h, int j,
    const float* __restrict__ A1p, const float* __restrict__ A2p,
    const float* __restrict__ A3p, const float* __restrict__ A4p,
    const float* __restrict__ B1p, const float* __restrict__ B2p,
    const float* __restrict__ C1p, const float* __restrict__ C2p)
{
    float2 a1r = *(const float2*)(A1p + 2 * h);
    float2 a2r = *(const float2*)(A2p + 2 * h);
    float2 a3r = *(const float2*)(A3p + 2 * h);
    float2 a4r = *(const float2*)(A4p + 2 * h);
    float2 b1r = *(const float2*)(B1p + 2 * h);
    float2 b2r = *(const float2*)(B2p + 2 * h);
    float2 c1r = *(const float2*)(C1p + 2 * h);
    float2 c2r = *(const float2*)(C2p + 2 * h);
    // compute per-lane (identical on all lanes: h is wave-uniform), then pin
    float a1v0 = sigm(a1r.x), a1v1 = sigm(a1r.y);
    float a2n0 = sigm(a2r.x), a2n1 = sigm(a2r.y);
    float a3v0 = sigm(a3r.x), a3v1 = sigm(a3r.y);
    float a4v0 = sigm(a4r.x), a4v1 = sigm(a4r.y);
    float b1v0 = sigm(b1r.x), b1v1 = sigm(b1r.y);
    float b2v0 = sigm(b2r.x), b2v1 = sigm(b2r.y);
    float c1v0 = SCALE * c1r.x, c1v1 = SCALE * c1r.y;
    float c2v0 = SCALE * c2r.x, c2v1 = SCALE * c2r.y;
    float p2v0 = a1v0 * a1v0, p4v0 = p2v0 * p2v0, p8v0 = p4v0 * p4v0;
    float p2v1 = a1v1 * a1v1, p4v1 = p2v1 * p2v1, p8v1 = p4v1 * p4v1;

    P.a1_0 = rfl(a1v0); P.a1_1 = rfl(a1v1);
    P.p2_0 = rfl(p2v0); P.p2_1 = rfl(p2v1);
    P.p4_0 = rfl(p4v0); P.p4_1 = rfl(p4v1);
    P.p8_0 = rfl(p8v0); P.p8_1 = rfl(p8v1);
    P.a3_0 = rfl(a3v0); P.a3_1 = rfl(a3v1);
    P.a4_0 = rfl(a4v0); P.a4_1 = rfl(a4v1);
    P.b1_0 = rfl(b1v0); P.b1_1 = rfl(b1v1);
    P.b2_0 = rfl(b2v0); P.b2_1 = rfl(b2v1);
    P.a3b1_0 = rfl(a3v0 * b1v0); P.a3b1_1 = rfl(a3v1 * b1v1);
    P.c1s0 = rfl(c1v0); P.c1s1 = rfl(c1v1);
    P.c2s0 = rfl(c2v0); P.c2s1 = rfl(c2v1);
    P.k00  = rfl(c1v0 * b1v0 + c1v1 * b1v1 + c2v0 * b2v0 + c2v1 * b2v1);

    // boundary kill: fwd at j==0 (also kills wave_shr cross-half leak),
    // rev at j==31 (kills wave_shl cross-half leak). Per-lane.
    const bool edge = REV ? (j == 31) : (j == 0);
    P.a2z0 = edge ? 0.f : a2n0;
    P.a2z1 = edge ? 0.f : a2n1;
    P.ab0  = P.a2z0 * P.b2_0; P.ab1 = P.a2z1 * P.b2_1;
    if (REV) {
        P.w_0 = ((j & 16) == 0) ? __powf(P.a1_0, (float)(16 - (j & 15))) : 0.f;
        P.w_1 = ((j & 16) == 0) ? __powf(P.a1_1, (float)(16 - (j & 15))) : 0.f;
    } else {
        P.w_0 = __powf(P.a1_0, (float)((j & 15) + 1));
        P.w_1 = __powf(P.a1_1, (float)((j & 15) + 1));
    }
}

// up passed by VALUE (same u sequence for both dirs in a pass; caller updates).
template<bool REV>
__device__ __forceinline__ float dir_step(const DirP& P, float u, float up,
    float& xh0, float& xh1, float& xv0, float& xv1, float& cx0, float& cx1)
{
    float b2u0 = P.b2_0 * u, b2u1 = P.b2_1 * u;
    float nxv0 = fmaf(P.a3_0, xh0, fmaf(P.a4_0, xv0, b2u0));
    float nxv1 = fmaf(P.a3_1, xh1, fmaf(P.a4_1, xv1, b2u1));
    float ncx0 = fmaf(P.a3b1_0, up, fmaf(P.a4_0, cx0, b2u0));
    float ncx1 = fmaf(P.a3b1_1, up, fmaf(P.a4_1, cx1, b2u1));
    float xl0, xl1, ul;
    if (REV) {   // neighbor = column j+1 -> wave_shl:1
        xl0 = dppf<0x130, 0xF, true>(nxv0);
        xl1 = dppf<0x130, 0xF, true>(nxv1);
        ul  = dppf<0x130, 0xF, true>(u);
    } else {     // neighbor = column j-1 -> wave_shr:1
        xl0 = dppf<0x138, 0xF, true>(nxv0);
        xl1 = dppf<0x138, 0xF, true>(nxv1);
        ul  = dppf<0x138, 0xF, true>(u);
    }
    float b1u0 = P.b1_0 * u, b1u1 = P.b1_1 * u;
    float d0 = fmaf(P.a2z0, xl0, b1u0);
    float d1 = fmaf(P.a2z1, xl1, b1u1);
    float e0 = fmaf(P.ab0, ul, b1u0);
    float e1 = fmaf(P.ab1, ul, b1u1);
    float nh0, nh1, rh0, rh1;
    if (REV) {
        nh0 = scanR(d0, P.a1_0, P.p2_0, P.p4_0, P.p8_0, P.w_0);
        nh1 = scanR(d1, P.a1_1, P.p2_1, P.p4_1, P.p8_1, P.w_1);
        rh0 = scanR(e0, P.a1_0, P.p2_0, P.p4_0, P.p8_0, P.w_0);
        rh1 = scanR(e1, P.a1_1, P.p2_1, P.p4_1, P.p8_1, P.w_1);
    } else {
        nh0 = scanF(d0, P.a1_0, P.p2_0, P.p4_0, P.p8_0, P.w_0);
        nh1 = scanF(d1, P.a1_1, P.p2_1, P.p4_1, P.p8_1, P.w_1);
        rh0 = scanF(e0, P.a1_0, P.p2_0, P.p4_0, P.p8_0, P.w_0);
        rh1 = scanF(e1, P.a1_1, P.p2_1, P.p4_1, P.p8_1, P.w_1);
    }
    float y = fmaf(P.c1s0, nh0 + rh0, fmaf(P.c1s1, nh1 + rh1,
              fmaf(P.c2s0, nxv0 + ncx0, fmaf(P.c2s1, nxv1 + ncx1, -P.k00 * u))));
    xh0 = nh0; xh1 = nh1; xv0 = nxv0; xv1 = nxv1; cx0 = ncx0; cx1 = ncx1;
    return y;
}

__global__ __launch_bounds__(THREADS) void ssm2d_kernel(
    const float* __restrict__ x,
    const float* __restrict__ A1p, const float* __restrict__ A2p,
    const float* __restrict__ A3p, const float* __restrict__ A4p,
    const float* __restrict__ B1p, const float* __restrict__ B2p,
    const float* __restrict__ C1p, const float* __restrict__ C2p,
    const float* __restrict__ omega,
    float* __restrict__ out)
{
    __shared__ float  u_lds[NPB * 1024];   // 32 KB, XOR-swizzled
    __shared__ __half a_lds[NPB * 1024];   // 16 KB fp16 accumulator
    const int t = threadIdx.x;

    // ---- block -> m mapping (wave-uniform h) ----
    // m = b*1024 + q*64 + hh, hh in 0..63.  Block covers: b fixed, q in
    // {q0, q0+1}, hh in {h0..h0+3}.  Image slot img (0..7):
    //   m(img) = m_base + (img&1)*64 + (img>>1)
    // so a wave's two half-images (img, img+1 with img even... img = 2w,2w+1)
    // differ by 64 in m -> SAME h -> SSM params wave-uniform -> SGPRs.
    // XCD swizzle: bid&7 picks h0-group so neighboring-m blocks share an XCD L2.
    const int bid  = blockIdx.x;
    const int xcd  = bid & 7;
    const int g    = (bid >> 3) & 1;
    const int rest = bid >> 4;               // 0..127
    const int bb   = rest & 15;              // batch index 0..15
    const int q0   = ((rest >> 4) << 1);     // 0,2,...,14 (q0+1 <= 15, no wrap)
    const int h0   = ((xcd << 1) | g) << 2;  // 0,4,...,60
    const int m_base = bb * 1024 + q0 * 64 + h0;

    // ---- stage x into LDS; XOR swizzle (pix ^ 4*img) kills 8-way conflicts ----
    const int simg = t & 7;
    const int m_s  = m_base + ((simg & 1) << 6) + (simg >> 1);
    #pragma unroll 4
    for (int it = 0; it < 32; ++it) {
        int pix = it * 32 + (t >> 3);
        u_lds[simg * 1024 + (pix ^ (simg << 2))] = x[(size_t)pix * M_TOT + m_s];
    }
    __syncthreads();

    const int j    = t & 31;
    const int img  = t >> 5;
    const int m    = m_base + ((img & 1) << 6) + (img >> 1);
    const int h    = m & 63;              // wave-uniform by construction
    const int colx = j ^ (img << 2);      // per-lane swizzled column
    const float*  uim = u_lds + img * 1024;
    __half*       aim = a_lds + img * 1024;
    const float om = omega[m & 1023];     // per-lane (q differs across halves)

    // ============ pass A: rows ascending, d0 (fwd) + d2 (rev) ============
    {
        DirP P0, P2;
        dir_init<false>(P0, h,       j, A1p, A2p, A3p, A4p, B1p, B2p, C1p, C2p);
        dir_init<true >(P2, 128 + h, j, A1p, A2p, A3p, A4p, B1p, B2p, C1p, C2p);
        float xh0a=0,xh1a=0,xv0a=0,xv1a=0,cx0a=0,cx1a=0;
        float xh0b=0,xh1b=0,xv0b=0,xv1b=0,cx0b=0,cx1b=0;
        float up = 0.f;
        #pragma unroll 4
        for (int s = 0; s < 32; ++s) {
            float u  = uim[s * 32 + colx];
            float y0 = dir_step<false>(P0, u, up, xh0a, xh1a, xv0a, xv1a, cx0a, cx1a);
            float y2 = dir_step<true >(P2, u, up, xh0b, xh1b, xv0b, xv1b, cx0b, cx1b);
            aim[s * 32 + colx] = __float2half(fmaf(u, om, y0 + y2));
            up = u;
        }
    }
    // ==== pass B: rows descending, d1 (fwd) + d3 (rev) + SiLU finalize ====
    {
        DirP P1, P3;
        dir_init<false>(P1, 64 + h,  j, A1p, A2p, A3p, A4p, B1p, B2p, C1p, C2p);
        dir_init<true >(P3, 192 + h, j, A1p, A2p, A3p, A4p, B1p, B2p, C1p, C2p);
        float xh0a=0,xh1a=0,xv0a=0,xv1a=0,cx0a=0,cx1a=0;
        float xh0b=0,xh1b=0,xv0b=0,xv1b=0,cx0b=0,cx1b=0;
        float up = 0.f;
        #pragma unroll 4
        for (int s = 0; s < 32; ++s) {
            int   r  = 31 - s;
            float u  = uim[r * 32 + colx];
            float y1 = dir_step<false>(P1, u, up, xh0a, xh1a, xv0a, xv1a, cx0a, cx1a);
            float y3 = dir_step<true >(P3, u, up, xh0b, xh1b, xv0b, xv1b, cx0b, cx1b);
            float z  = __half2float(aim[r * 32 + colx]) + y1 + y3;
            float sg = 1.0f / (1.0f + __expf(-z));
            aim[r * 32 + colx] = __float2half(z * sg);   // in-place finalize
            up = u;
        }
    }
    __syncthreads();

    // ---- coalesced store-out (fp16 -> f32) ----
    #pragma unroll 4
    for (int it = 0; it < 32; ++it) {
        int pix = it * 32 + (t >> 3);
        out[(size_t)pix * M_TOT + m_s] =
            __half2float(a_lds[simg * 1024 + (pix ^ (simg << 2))]);
    }
}

extern "C" void kernel_launch(void* const* d_in, const int* in_sizes, int n_in,
                              void* d_out, int out_size, void* d_ws, size_t ws_size,
                              hipStream_t stream) {
    const float* x  = (const float*)d_in[0];
    const float* A1 = (const float*)d_in[1];
    const float* A2 = (const float*)d_in[2];
    const float* A3 = (const float*)d_in[3];
    const float* A4 = (const float*)d_in[4];
    const float* B1 = (const float*)d_in[5];
    const float* B2 = (const float*)d_in[6];
    const float* C1 = (const float*)d_in[7];
    const float* C2 = (const float*)d_in[8];
    const float* om = (const float*)d_in[9];
    float* out = (float*)d_out;
    hipLaunchKernelGGL(ssm2d_kernel, dim3(M_TOT / NPB), dim3(THREADS), 0, stream,
                       x, A1, A2, A3, A4, B1, B2, C1, C2, om, out);
}

// Round 2
// 245.130 us; speedup vs baseline: 1.0664x; 1.0664x over previous
//
#include <hip/hip_runtime.h>
#include <hip/hip_fp16.h>

// TwoDimensionalSSM via direct 2D recurrence. Round 8: packed-FP32 math.
// R7 post-mortem: SGPR-pinning + h-uniform remap was NEUTRAL on time (175.7 vs
// 176.2 us) while quadrupling FETCH_SIZE (coalescing broken) -> remat theory
// wrong, kernel is pure VALU-issue-bound. New lever: gfx950 full-rate packed
// fp32 (v_pk_fma_f32 / v_pk_mul_f32, VOP3P). All math here comes in natural
// (n=0,n=1) pairs -> pack states/coeffs/scan values as <2 x float>:
//   - recurrence+dot per dir_step: ~28 scalar -> ~16 packed issues
//   - scan step-pair: 2 dpp + 2 fma -> 2 dpp + 1 pk_fma
//   - fold the two -k00*u terms per pass into one hoisted scalar
// Mapping/staging/store reverted EXACTLY to the proven R6 coalesced form
// (FETCH back to ~33 MB). No readfirstlane. Scan DPP controls unchanged.

#define NPB 8            // images per block (one per 32-lane half, 2/wave)
#define THREADS 256
#define M_TOT 16384      // B*E
#define SCALE 0.70710678118654752f  // sqrt(1/N), N=2

typedef __attribute__((ext_vector_type(2))) float v2f;

__device__ __forceinline__ v2f v2s(float s) { return (v2f){s, s}; }
__device__ __forceinline__ v2f pfma(v2f a, v2f b, v2f c) {
    return __builtin_elementwise_fma(a, b, c);   // -> v_pk_fma_f32
}

template<int CTRL, int ROW_MASK, bool BC>
__device__ __forceinline__ float dppf(float v) {
    return __int_as_float(__builtin_amdgcn_update_dpp(
        0, __float_as_int(v), CTRL, ROW_MASK, 0xF, BC));
}
template<int CTRL, int ROW_MASK, bool BC>
__device__ __forceinline__ v2f dpp2(v2f v) {
    v2f r;
    r.x = dppf<CTRL, ROW_MASK, BC>(v.x);
    r.y = dppf<CTRL, ROW_MASK, BC>(v.y);
    return r;
}
__device__ __forceinline__ v2f swz2(v2f v) {   // lane16 of each 32-half
    v2f r;
    r.x = __int_as_float(__builtin_amdgcn_ds_swizzle(__float_as_int(v.x), 0x0200));
    r.y = __int_as_float(__builtin_amdgcn_ds_swizzle(__float_as_int(v.y), 0x0200));
    return r;
}

__device__ __forceinline__ float sigm(float v) { return 1.0f / (1.0f + __expf(-v)); }

struct DirP2 {
    v2f a1, p2, p4, p8, w;        // scan coefficients
    v2f a2z, ab, a3, a4, b1, b2, a3b1, c1s, c2s;
    float k00;
};

// forward inclusive scan over each 32-lane half (packed pair)
__device__ __forceinline__ v2f scanF2(v2f v, const DirP2& P) {
    v = pfma(P.a1, dpp2<0x111, 0xF, true >(v), v);  // row_shr:1
    v = pfma(P.p2, dpp2<0x112, 0xF, true >(v), v);  // row_shr:2
    v = pfma(P.p4, dpp2<0x114, 0xF, true >(v), v);  // row_shr:4
    v = pfma(P.p8, dpp2<0x118, 0xF, true >(v), v);  // row_shr:8
    v = pfma(P.w,  dpp2<0x142, 0xA, false>(v), v);  // row_bcast15 -> rows 1,3
    return v;
}
// reverse inclusive scan over each 32-lane half (packed pair)
__device__ __forceinline__ v2f scanR2(v2f v, const DirP2& P) {
    v = pfma(P.a1, dpp2<0x101, 0xF, true>(v), v);   // row_shl:1
    v = pfma(P.p2, dpp2<0x102, 0xF, true>(v), v);   // row_shl:2
    v = pfma(P.p4, dpp2<0x104, 0xF, true>(v), v);   // row_shl:4
    v = pfma(P.p8, dpp2<0x108, 0xF, true>(v), v);   // row_shl:8
    v = pfma(P.w,  swz2(v), v);
    return v;
}

template<bool REV>
__device__ __forceinline__ void dir_init2(DirP2& P, int h, int j,
    const float* __restrict__ A1p, const float* __restrict__ A2p,
    const float* __restrict__ A3p, const float* __restrict__ A4p,
    const float* __restrict__ B1p, const float* __restrict__ B2p,
    const float* __restrict__ C1p, const float* __restrict__ C2p)
{
    float2 a1r = *(const float2*)(A1p + 2 * h);
    float2 a2r = *(const float2*)(A2p + 2 * h);
    float2 a3r = *(const float2*)(A3p + 2 * h);
    float2 a4r = *(const float2*)(A4p + 2 * h);
    float2 b1r = *(const float2*)(B1p + 2 * h);
    float2 b2r = *(const float2*)(B2p + 2 * h);
    float2 c1r = *(const float2*)(C1p + 2 * h);
    float2 c2r = *(const float2*)(C2p + 2 * h);
    float a1v0 = sigm(a1r.x), a1v1 = sigm(a1r.y);
    P.a1 = (v2f){a1v0, a1v1};
    P.p2 = P.a1 * P.a1; P.p4 = P.p2 * P.p2; P.p8 = P.p4 * P.p4;
    P.a3 = (v2f){sigm(a3r.x), sigm(a3r.y)};
    P.a4 = (v2f){sigm(a4r.x), sigm(a4r.y)};
    P.b1 = (v2f){sigm(b1r.x), sigm(b1r.y)};
    P.b2 = (v2f){sigm(b2r.x), sigm(b2r.y)};
    P.a3b1 = P.a3 * P.b1;
    P.c1s = (v2f){SCALE * c1r.x, SCALE * c1r.y};
    P.c2s = (v2f){SCALE * c2r.x, SCALE * c2r.y};
    v2f kk = P.c1s * P.b1 + P.c2s * P.b2;
    P.k00 = kk.x + kk.y;
    // boundary kill: fwd at j==0 (also kills wave_shr cross-half leak),
    // rev at j==31 (kills wave_shl cross-half leak). Per-lane.
    const bool edge = REV ? (j == 31) : (j == 0);
    v2f a2n = (v2f){sigm(a2r.x), sigm(a2r.y)};
    P.a2z = edge ? (v2f){0.f, 0.f} : a2n;
    P.ab  = P.a2z * P.b2;
    if (REV) {
        if ((j & 16) == 0) {
            float e = (float)(16 - (j & 15));
            P.w = (v2f){__powf(a1v0, e), __powf(a1v1, e)};
        } else {
            P.w = (v2f){0.f, 0.f};
        }
    } else {
        float e = (float)((j & 15) + 1);
        P.w = (v2f){__powf(a1v0, e), __powf(a1v1, e)};
    }
}

// u2/up2 pre-splatted by caller (shared by both directions of a pass).
// Returns the y contribution WITHOUT the -k00*u term (caller folds it).
template<bool REV>
__device__ __forceinline__ float dir_step2(const DirP2& P, v2f u2, v2f up2,
    v2f& xh, v2f& xv, v2f& cx)
{
    v2f b2u = P.b2 * u2;                              // pk_mul
    v2f nxv = pfma(P.a3, xh, pfma(P.a4, xv, b2u));    // 2x pk_fma
    v2f ncx = pfma(P.a3b1, up2, pfma(P.a4, cx, b2u)); // 2x pk_fma
    v2f xl, ul2;
    if constexpr (REV) {   // neighbor = column j+1 -> wave_shl:1
        xl  = dpp2<0x130, 0xF, true>(nxv);
        ul2 = dpp2<0x130, 0xF, true>(u2);
    } else {               // neighbor = column j-1 -> wave_shr:1
        xl  = dpp2<0x138, 0xF, true>(nxv);
        ul2 = dpp2<0x138, 0xF, true>(u2);
    }
    v2f b1u = P.b1 * u2;                              // pk_mul
    v2f d = pfma(P.a2z, xl, b1u);
    v2f e = pfma(P.ab, ul2, b1u);
    v2f nh, rh;
    if constexpr (REV) { nh = scanR2(d, P); rh = scanR2(e, P); }
    else               { nh = scanF2(d, P); rh = scanF2(e, P); }
    v2f acc = pfma(P.c1s, nh + rh, P.c2s * (nxv + ncx));
    xh = nh; xv = nxv; cx = ncx;
    return acc.x + acc.y;
}

__global__ __launch_bounds__(THREADS) void ssm2d_kernel(
    const float* __restrict__ x,
    const float* __restrict__ A1p, const float* __restrict__ A2p,
    const float* __restrict__ A3p, const float* __restrict__ A4p,
    const float* __restrict__ B1p, const float* __restrict__ B2p,
    const float* __restrict__ C1p, const float* __restrict__ C2p,
    const float* __restrict__ omega,
    float* __restrict__ out)
{
    __shared__ float  u_lds[NPB * 1024];   // 32 KB, XOR-swizzled
    __shared__ __half a_lds[NPB * 1024];   // 16 KB fp16 accumulator
    const int t = threadIdx.x;
    // XCD-aware remap (R6 proven form): blocks on the same XCD cover adjacent
    // m-ranges so both halves of each 64B x-line hit the same L2.
    const int bid = blockIdx.x;
    const int m0  = ((bid & 7) * 256 + (bid >> 3)) * NPB;

    // ---- stage x into LDS; XOR swizzle (pix ^ 4*img) kills 8-way conflicts ----
    const int simg = t & 7;
    #pragma unroll 4
    for (int it = 0; it < 32; ++it) {
        int pix = it * 32 + (t >> 3);
        u_lds[simg * 1024 + (pix ^ (simg << 2))] = x[(size_t)pix * M_TOT + (m0 + simg)];
    }
    __syncthreads();

    const int j    = t & 31;
    const int img  = t >> 5;
    const int m    = m0 + img;
    const int hb   = m & 63;
    const int colx = j ^ (img << 2);      // per-lane swizzled column
    const float*  uim = u_lds + img * 1024;
    __half*       aim = a_lds + img * 1024;
    const float om = omega[m & 1023];

    // ============ pass A: rows ascending, d0 (fwd) + d2 (rev) ============
    {
        DirP2 P0, P2;
        dir_init2<false>(P0, hb,       j, A1p, A2p, A3p, A4p, B1p, B2p, C1p, C2p);
        dir_init2<true >(P2, 128 + hb, j, A1p, A2p, A3p, A4p, B1p, B2p, C1p, C2p);
        const float omA = om - P0.k00 - P2.k00;   // fold both -k00*u terms
        v2f xhA = {0,0}, xvA = {0,0}, cxA = {0,0};
        v2f xhB = {0,0}, xvB = {0,0}, cxB = {0,0};
        float up = 0.f;
        #pragma unroll 4
        for (int s = 0; s < 32; ++s) {
            float u  = uim[s * 32 + colx];
            v2f u2 = v2s(u), up2 = v2s(up);
            float y0 = dir_step2<false>(P0, u2, up2, xhA, xvA, cxA);
            float y2 = dir_step2<true >(P2, u2, up2, xhB, xvB, cxB);
            aim[s * 32 + colx] = __float2half(fmaf(u, omA, y0 + y2));
            up = u;
        }
    }
    // ==== pass B: rows descending, d1 (fwd) + d3 (rev) + SiLU finalize ====
    {
        DirP2 P1, P3;
        dir_init2<false>(P1, 64 + hb,  j, A1p, A2p, A3p, A4p, B1p, B2p, C1p, C2p);
        dir_init2<true >(P3, 192 + hb, j, A1p, A2p, A3p, A4p, B1p, B2p, C1p, C2p);
        const float kB = P1.k00 + P3.k00;
        v2f xhA = {0,0}, xvA = {0,0}, cxA = {0,0};
        v2f xhB = {0,0}, xvB = {0,0}, cxB = {0,0};
        float up = 0.f;
        #pragma unroll 4
        for (int s = 0; s < 32; ++s) {
            int   r  = 31 - s;
            float u  = uim[r * 32 + colx];
            v2f u2 = v2s(u), up2 = v2s(up);
            float y1 = dir_step2<false>(P1, u2, up2, xhA, xvA, cxA);
            float y3 = dir_step2<true >(P3, u2, up2, xhB, xvB, cxB);
            float z  = __half2float(aim[r * 32 + colx]) + y1 + y3;
            z = fmaf(u, -kB, z);
            float sg = 1.0f / (1.0f + __expf(-z));
            aim[r * 32 + colx] = __float2half(z * sg);   // in-place finalize
            up = u;
        }
    }
    __syncthreads();

    // ---- coalesced store-out (fp16 -> f32) ----
    #pragma unroll 4
    for (int it = 0; it < 32; ++it) {
        int pix = it * 32 + (t >> 3);
        out[(size_t)pix * M_TOT + (m0 + simg)] =
            __half2float(a_lds[simg * 1024 + (pix ^ (simg << 2))]);
    }
}

extern "C" void kernel_launch(void* const* d_in, const int* in_sizes, int n_in,
                              void* d_out, int out_size, void* d_ws, size_t ws_size,
                              hipStream_t stream) {
    const float* x  = (const float*)d_in[0];
    const float* A1 = (const float*)d_in[1];
    const float* A2 = (const float*)d_in[2];
    const float* A3 = (const float*)d_in[3];
    const float* A4 = (const float*)d_in[4];
    const float* B1 = (const float*)d_in[5];
    const float* B2 = (const float*)d_in[6];
    const float* C1 = (const float*)d_in[7];
    const float* C2 = (const float*)d_in[8];
    const float* om = (const float*)d_in[9];
    float* out = (float*)d_out;
    hipLaunchKernelGGL(ssm2d_kernel, dim3(M_TOT / NPB), dim3(THREADS), 0, stream,
                       x, A1, A2, A3, A4, B1, B2, C1, C2, om, out);
}

// Round 3
// 227.379 us; speedup vs baseline: 1.1497x; 1.0781x over previous
//
#include <hip/hip_runtime.h>
#include <hip/hip_fp16.h>

// TwoDimensionalSSM via direct 2D recurrence. Round 9: fused DPP-scan asm +
// fp16 u_lds for occupancy.
// R8 post-mortem: packed fp32 cut VALU busy-time 150->134us but dur 176->181:
// VOP3P can't take DPP -> packed scan stage = mov_dpp,mov_dpp,pk_fma (2-deep
// chain) vs scalar fmac_dpp (1). Kernel became latency-bound at 2.4 waves/SIMD
// (LDS 48KB caps 3 blocks/CU). Fixes:
//  (1) scans as ONE asm block of v_fmac_f32_dpp, 8 independent chains
//      ({d,e} x {fwd,rev} x {n0,n1}) interleaved 8-wide -> DPP 2-wait-state
//      hazard covered by construction; s_nop 1 guards asm entry. Masked
//      row_bcast:15 fmac (row_mask 0xa) == proven mov+fma form (unwritten
//      rows keep acc = adding w*0).
//  (2) u_lds fp16: block LDS 48->32KB -> 5 blocks/CU (20 waves, was 12).
//      fp16-u error (~5e-4 rel) < accepted fp16-acc roundtrip error.
// Recurrence/dot stays packed v2f (no DPP involved). Mapping/staging/store
// structure unchanged from proven R6/R8 coalesced form.

#define NPB 8            // images per block (one per 32-lane half, 2/wave)
#define THREADS 256
#define M_TOT 16384      // B*E
#define SCALE 0.70710678118654752f  // sqrt(1/N), N=2

typedef __attribute__((ext_vector_type(2))) float v2f;

__device__ __forceinline__ v2f v2s(float s) { return (v2f){s, s}; }
__device__ __forceinline__ v2f pfma(v2f a, v2f b, v2f c) {
    return __builtin_elementwise_fma(a, b, c);   // -> v_pk_fma_f32
}

template<int CTRL, int ROW_MASK, bool BC>
__device__ __forceinline__ float dppf(float v) {
    return __int_as_float(__builtin_amdgcn_update_dpp(
        0, __float_as_int(v), CTRL, ROW_MASK, 0xF, BC));
}
template<int CTRL, int ROW_MASK, bool BC>
__device__ __forceinline__ v2f dpp2(v2f v) {
    v2f r;
    r.x = dppf<CTRL, ROW_MASK, BC>(v.x);
    r.y = dppf<CTRL, ROW_MASK, BC>(v.y);
    return r;
}
__device__ __forceinline__ v2f swz2(v2f v) {   // lane16 of each 32-half
    v2f r;
    r.x = __int_as_float(__builtin_amdgcn_ds_swizzle(__float_as_int(v.x), 0x0200));
    r.y = __int_as_float(__builtin_amdgcn_ds_swizzle(__float_as_int(v.y), 0x0200));
    return r;
}

__device__ __forceinline__ float sigm(float v) { return 1.0f / (1.0f + __expf(-v)); }

struct DirP2 {
    v2f a1, p2, p4, p8, w;        // scan coefficients
    v2f a2z, ab, a3, a4, b1, b2, a3b1, c1s, c2s;
    float k00;
};

template<bool REV>
__device__ __forceinline__ void dir_init2(DirP2& P, int h, int j,
    const float* __restrict__ A1p, const float* __restrict__ A2p,
    const float* __restrict__ A3p, const float* __restrict__ A4p,
    const float* __restrict__ B1p, const float* __restrict__ B2p,
    const float* __restrict__ C1p, const float* __restrict__ C2p)
{
    float2 a1r = *(const float2*)(A1p + 2 * h);
    float2 a2r = *(const float2*)(A2p + 2 * h);
    float2 a3r = *(const float2*)(A3p + 2 * h);
    float2 a4r = *(const float2*)(A4p + 2 * h);
    float2 b1r = *(const float2*)(B1p + 2 * h);
    float2 b2r = *(const float2*)(B2p + 2 * h);
    float2 c1r = *(const float2*)(C1p + 2 * h);
    float2 c2r = *(const float2*)(C2p + 2 * h);
    float a1v0 = sigm(a1r.x), a1v1 = sigm(a1r.y);
    P.a1 = (v2f){a1v0, a1v1};
    P.p2 = P.a1 * P.a1; P.p4 = P.p2 * P.p2; P.p8 = P.p4 * P.p4;
    P.a3 = (v2f){sigm(a3r.x), sigm(a3r.y)};
    P.a4 = (v2f){sigm(a4r.x), sigm(a4r.y)};
    P.b1 = (v2f){sigm(b1r.x), sigm(b1r.y)};
    P.b2 = (v2f){sigm(b2r.x), sigm(b2r.y)};
    P.a3b1 = P.a3 * P.b1;
    P.c1s = (v2f){SCALE * c1r.x, SCALE * c1r.y};
    P.c2s = (v2f){SCALE * c2r.x, SCALE * c2r.y};
    v2f kk = P.c1s * P.b1 + P.c2s * P.b2;
    P.k00 = kk.x + kk.y;
    // boundary kill: fwd at j==0 (also kills wave_shr cross-half leak),
    // rev at j==31 (kills wave_shl cross-half leak). Per-lane.
    const bool edge = REV ? (j == 31) : (j == 0);
    v2f a2n = (v2f){sigm(a2r.x), sigm(a2r.y)};
    P.a2z = edge ? (v2f){0.f, 0.f} : a2n;
    P.ab  = P.a2z * P.b2;
    if (REV) {
        if ((j & 16) == 0) {
            float e = (float)(16 - (j & 15));
            P.w = (v2f){__powf(a1v0, e), __powf(a1v1, e)};
        } else {
            P.w = (v2f){0.f, 0.f};
        }
    } else {
        float e = (float)((j & 15) + 1);
        P.w = (v2f){__powf(a1v0, e), __powf(a1v1, e)};
    }
}

// recurrence front-end: produce nxv, ncx and the two scan inputs d, e
template<bool REV>
__device__ __forceinline__ void dir_pre(const DirP2& P, v2f u2, v2f up2,
    v2f xh, v2f xv, v2f cx, v2f& nxv, v2f& ncx, v2f& d, v2f& e)
{
    v2f b2u = P.b2 * u2;
    nxv = pfma(P.a3, xh, pfma(P.a4, xv, b2u));
    ncx = pfma(P.a3b1, up2, pfma(P.a4, cx, b2u));
    v2f xl, ul2;
    if constexpr (REV) {   // neighbor = column j+1 -> wave_shl:1
        xl  = dpp2<0x130, 0xF, true>(nxv);
        ul2 = dpp2<0x130, 0xF, true>(u2);
    } else {               // neighbor = column j-1 -> wave_shr:1
        xl  = dpp2<0x138, 0xF, true>(nxv);
        ul2 = dpp2<0x138, 0xF, true>(u2);
    }
    v2f b1u = P.b1 * u2;
    d = pfma(P.a2z, xl, b1u);
    e = pfma(P.ab, ul2, b1u);
}

// dot + state update
__device__ __forceinline__ float dir_post(const DirP2& P, v2f nh, v2f rh,
    v2f nxv, v2f ncx, v2f& xh, v2f& xv, v2f& cx)
{
    v2f acc = pfma(P.c1s, nh + rh, P.c2s * (nxv + ncx));
    xh = nh; xv = nxv; cx = ncx;
    return acc.x + acc.y;
}

// 8 interleaved scan chains: f* = fwd (row_shr + bcast15), r* = rev
// (row_shl; lane16-broadcast tail done by caller via ds_swizzle).
// One v_fmac_f32_dpp per stage per chain; 8-wide interleave covers the
// DPP read-after-VALU-write hazard; s_nop 1 covers the asm entry edge.
__device__ __forceinline__ void scan8(
    float& f0, float& f1, float& f2, float& f3,
    float& r0, float& r1, float& r2, float& r3,
    const DirP2& PF, const DirP2& PR)
{
    asm("s_nop 1\n\t"
        // ---- stage 1 ----
        "v_fmac_f32_dpp %0, %0, %8  row_shr:1 row_mask:0xf bank_mask:0xf bound_ctrl:0\n\t"
        "v_fmac_f32_dpp %1, %1, %9  row_shr:1 row_mask:0xf bank_mask:0xf bound_ctrl:0\n\t"
        "v_fmac_f32_dpp %2, %2, %8  row_shr:1 row_mask:0xf bank_mask:0xf bound_ctrl:0\n\t"
        "v_fmac_f32_dpp %3, %3, %9  row_shr:1 row_mask:0xf bank_mask:0xf bound_ctrl:0\n\t"
        "v_fmac_f32_dpp %4, %4, %18 row_shl:1 row_mask:0xf bank_mask:0xf bound_ctrl:0\n\t"
        "v_fmac_f32_dpp %5, %5, %19 row_shl:1 row_mask:0xf bank_mask:0xf bound_ctrl:0\n\t"
        "v_fmac_f32_dpp %6, %6, %18 row_shl:1 row_mask:0xf bank_mask:0xf bound_ctrl:0\n\t"
        "v_fmac_f32_dpp %7, %7, %19 row_shl:1 row_mask:0xf bank_mask:0xf bound_ctrl:0\n\t"
        // ---- stage 2 ----
        "v_fmac_f32_dpp %0, %0, %10 row_shr:2 row_mask:0xf bank_mask:0xf bound_ctrl:0\n\t"
        "v_fmac_f32_dpp %1, %1, %11 row_shr:2 row_mask:0xf bank_mask:0xf bound_ctrl:0\n\t"
        "v_fmac_f32_dpp %2, %2, %10 row_shr:2 row_mask:0xf bank_mask:0xf bound_ctrl:0\n\t"
        "v_fmac_f32_dpp %3, %3, %11 row_shr:2 row_mask:0xf bank_mask:0xf bound_ctrl:0\n\t"
        "v_fmac_f32_dpp %4, %4, %20 row_shl:2 row_mask:0xf bank_mask:0xf bound_ctrl:0\n\t"
        "v_fmac_f32_dpp %5, %5, %21 row_shl:2 row_mask:0xf bank_mask:0xf bound_ctrl:0\n\t"
        "v_fmac_f32_dpp %6, %6, %20 row_shl:2 row_mask:0xf bank_mask:0xf bound_ctrl:0\n\t"
        "v_fmac_f32_dpp %7, %7, %21 row_shl:2 row_mask:0xf bank_mask:0xf bound_ctrl:0\n\t"
        // ---- stage 3 ----
        "v_fmac_f32_dpp %0, %0, %12 row_shr:4 row_mask:0xf bank_mask:0xf bound_ctrl:0\n\t"
        "v_fmac_f32_dpp %1, %1, %13 row_shr:4 row_mask:0xf bank_mask:0xf bound_ctrl:0\n\t"
        "v_fmac_f32_dpp %2, %2, %12 row_shr:4 row_mask:0xf bank_mask:0xf bound_ctrl:0\n\t"
        "v_fmac_f32_dpp %3, %3, %13 row_shr:4 row_mask:0xf bank_mask:0xf bound_ctrl:0\n\t"
        "v_fmac_f32_dpp %4, %4, %22 row_shl:4 row_mask:0xf bank_mask:0xf bound_ctrl:0\n\t"
        "v_fmac_f32_dpp %5, %5, %23 row_shl:4 row_mask:0xf bank_mask:0xf bound_ctrl:0\n\t"
        "v_fmac_f32_dpp %6, %6, %22 row_shl:4 row_mask:0xf bank_mask:0xf bound_ctrl:0\n\t"
        "v_fmac_f32_dpp %7, %7, %23 row_shl:4 row_mask:0xf bank_mask:0xf bound_ctrl:0\n\t"
        // ---- stage 4 ----
        "v_fmac_f32_dpp %0, %0, %14 row_shr:8 row_mask:0xf bank_mask:0xf bound_ctrl:0\n\t"
        "v_fmac_f32_dpp %1, %1, %15 row_shr:8 row_mask:0xf bank_mask:0xf bound_ctrl:0\n\t"
        "v_fmac_f32_dpp %2, %2, %14 row_shr:8 row_mask:0xf bank_mask:0xf bound_ctrl:0\n\t"
        "v_fmac_f32_dpp %3, %3, %15 row_shr:8 row_mask:0xf bank_mask:0xf bound_ctrl:0\n\t"
        "v_fmac_f32_dpp %4, %4, %24 row_shl:8 row_mask:0xf bank_mask:0xf bound_ctrl:0\n\t"
        "v_fmac_f32_dpp %5, %5, %25 row_shl:8 row_mask:0xf bank_mask:0xf bound_ctrl:0\n\t"
        "v_fmac_f32_dpp %6, %6, %24 row_shl:8 row_mask:0xf bank_mask:0xf bound_ctrl:0\n\t"
        "v_fmac_f32_dpp %7, %7, %25 row_shl:8 row_mask:0xf bank_mask:0xf bound_ctrl:0\n\t"
        // ---- stage 5, fwd only: rows 1,3 += w * lane15-of-prev-row ----
        "v_fmac_f32_dpp %0, %0, %16 row_bcast:15 row_mask:0xa bank_mask:0xf bound_ctrl:0\n\t"
        "v_fmac_f32_dpp %1, %1, %17 row_bcast:15 row_mask:0xa bank_mask:0xf bound_ctrl:0\n\t"
        "v_fmac_f32_dpp %2, %2, %16 row_bcast:15 row_mask:0xa bank_mask:0xf bound_ctrl:0\n\t"
        "v_fmac_f32_dpp %3, %3, %17 row_bcast:15 row_mask:0xa bank_mask:0xf bound_ctrl:0"
        : "+v"(f0), "+v"(f1), "+v"(f2), "+v"(f3),
          "+v"(r0), "+v"(r1), "+v"(r2), "+v"(r3)
        : "v"(PF.a1.x), "v"(PF.a1.y), "v"(PF.p2.x), "v"(PF.p2.y),
          "v"(PF.p4.x), "v"(PF.p4.y), "v"(PF.p8.x), "v"(PF.p8.y),
          "v"(PF.w.x),  "v"(PF.w.y),
          "v"(PR.a1.x), "v"(PR.a1.y), "v"(PR.p2.x), "v"(PR.p2.y),
          "v"(PR.p4.x), "v"(PR.p4.y), "v"(PR.p8.x), "v"(PR.p8.y));
}

__global__ __launch_bounds__(THREADS) void ssm2d_kernel(
    const float* __restrict__ x,
    const float* __restrict__ A1p, const float* __restrict__ A2p,
    const float* __restrict__ A3p, const float* __restrict__ A4p,
    const float* __restrict__ B1p, const float* __restrict__ B2p,
    const float* __restrict__ C1p, const float* __restrict__ C2p,
    const float* __restrict__ omega,
    float* __restrict__ out)
{
    __shared__ __half u_lds[NPB * 1024];   // 16 KB fp16 input, XOR-swizzled
    __shared__ __half a_lds[NPB * 1024];   // 16 KB fp16 accumulator
    const int t = threadIdx.x;
    // XCD-aware remap (R6 proven form)
    const int bid = blockIdx.x;
    const int m0  = ((bid & 7) * 256 + (bid >> 3)) * NPB;

    // ---- stage x into LDS (f32 -> fp16); XOR swizzle kills 8-way conflicts ----
    const int simg = t & 7;
    #pragma unroll 4
    for (int it = 0; it < 32; ++it) {
        int pix = it * 32 + (t >> 3);
        u_lds[simg * 1024 + (pix ^ (simg << 2))] =
            __float2half(x[(size_t)pix * M_TOT + (m0 + simg)]);
    }
    __syncthreads();

    const int j    = t & 31;
    const int img  = t >> 5;
    const int m    = m0 + img;
    const int hb   = m & 63;
    const int colx = j ^ (img << 2);      // per-lane swizzled column
    const __half* uim = u_lds + img * 1024;
    __half*       aim = a_lds + img * 1024;
    const float om = omega[m & 1023];

    // ============ pass A: rows ascending, d0 (fwd) + d2 (rev) ============
    {
        DirP2 P0, P2;
        dir_init2<false>(P0, hb,       j, A1p, A2p, A3p, A4p, B1p, B2p, C1p, C2p);
        dir_init2<true >(P2, 128 + hb, j, A1p, A2p, A3p, A4p, B1p, B2p, C1p, C2p);
        const float omA = om - P0.k00 - P2.k00;   // fold both -k00*u terms
        v2f xhF = {0,0}, xvF = {0,0}, cxF = {0,0};
        v2f xhR = {0,0}, xvR = {0,0}, cxR = {0,0};
        float up = 0.f;
        #pragma unroll 4
        for (int s = 0; s < 32; ++s) {
            float u  = __half2float(uim[s * 32 + colx]);
            v2f u2 = v2s(u), up2 = v2s(up);
            v2f nxvF, ncxF, dF, eF, nxvR, ncxR, dR, eR;
            dir_pre<false>(P0, u2, up2, xhF, xvF, cxF, nxvF, ncxF, dF, eF);
            dir_pre<true >(P2, u2, up2, xhR, xvR, cxR, nxvR, ncxR, dR, eR);
            float f0 = dF.x, f1 = dF.y, f2 = eF.x, f3 = eF.y;
            float r0 = dR.x, r1 = dR.y, r2 = eR.x, r3 = eR.y;
            scan8(f0, f1, f2, f3, r0, r1, r2, r3, P0, P2);
            v2f nhF = {f0, f1}, rhF = {f2, f3};
            v2f dRv = {r0, r1}, eRv = {r2, r3};
            dRv = pfma(P2.w, swz2(dRv), dRv);   // rev tail: lane16 broadcast
            eRv = pfma(P2.w, swz2(eRv), eRv);
            float y0 = dir_post(P0, nhF, rhF, nxvF, ncxF, xhF, xvF, cxF);
            float y2 = dir_post(P2, dRv, eRv, nxvR, ncxR, xhR, xvR, cxR);
            aim[s * 32 + colx] = __float2half(fmaf(u, omA, y0 + y2));
            up = u;
        }
    }
    // ==== pass B: rows descending, d1 (fwd) + d3 (rev) + SiLU finalize ====
    {
        DirP2 P1, P3;
        dir_init2<false>(P1, 64 + hb,  j, A1p, A2p, A3p, A4p, B1p, B2p, C1p, C2p);
        dir_init2<true >(P3, 192 + hb, j, A1p, A2p, A3p, A4p, B1p, B2p, C1p, C2p);
        const float kB = P1.k00 + P3.k00;
        v2f xhF = {0,0}, xvF = {0,0}, cxF = {0,0};
        v2f xhR = {0,0}, xvR = {0,0}, cxR = {0,0};
        float up = 0.f;
        #pragma unroll 4
        for (int s = 0; s < 32; ++s) {
            int   r  = 31 - s;
            float u  = __half2float(uim[r * 32 + colx]);
            v2f u2 = v2s(u), up2 = v2s(up);
            v2f nxvF, ncxF, dF, eF, nxvR, ncxR, dR, eR;
            dir_pre<false>(P1, u2, up2, xhF, xvF, cxF, nxvF, ncxF, dF, eF);
            dir_pre<true >(P3, u2, up2, xhR, xvR, cxR, nxvR, ncxR, dR, eR);
            float f0 = dF.x, f1 = dF.y, f2 = eF.x, f3 = eF.y;
            float r0 = dR.x, r1 = dR.y, r2 = eR.x, r3 = eR.y;
            scan8(f0, f1, f2, f3, r0, r1, r2, r3, P1, P3);
            v2f nhF = {f0, f1}, rhF = {f2, f3};
            v2f dRv = {r0, r1}, eRv = {r2, r3};
            dRv = pfma(P3.w, swz2(dRv), dRv);
            eRv = pfma(P3.w, swz2(eRv), eRv);
            float y1 = dir_post(P1, nhF, rhF, nxvF, ncxF, xhF, xvF, cxF);
            float y3 = dir_post(P3, dRv, eRv, nxvR, ncxR, xhR, xvR, cxR);
            float z  = __half2float(aim[r * 32 + colx]) + y1 + y3;
            z = fmaf(u, -kB, z);
            float sg = 1.0f / (1.0f + __expf(-z));
            aim[r * 32 + colx] = __float2half(z * sg);   // in-place finalize
            up = u;
        }
    }
    __syncthreads();

    // ---- coalesced store-out (fp16 -> f32) ----
    #pragma unroll 4
    for (int it = 0; it < 32; ++it) {
        int pix = it * 32 + (t >> 3);
        out[(size_t)pix * M_TOT + (m0 + simg)] =
            __half2float(a_lds[simg * 1024 + (pix ^ (simg << 2))]);
    }
}

extern "C" void kernel_launch(void* const* d_in, const int* in_sizes, int n_in,
                              void* d_out, int out_size, void* d_ws, size_t ws_size,
                              hipStream_t stream) {
    const float* x  = (const float*)d_in[0];
    const float* A1 = (const float*)d_in[1];
    const float* A2 = (const float*)d_in[2];
    const float* A3 = (const float*)d_in[3];
    const float* A4 = (const float*)d_in[4];
    const float* B1 = (const float*)d_in[5];
    const float* B2 = (const float*)d_in[6];
    const float* C1 = (const float*)d_in[7];
    const float* C2 = (const float*)d_in[8];
    const float* om = (const float*)d_in[9];
    float* out = (float*)d_out;
    hipLaunchKernelGGL(ssm2d_kernel, dim3(M_TOT / NPB), dim3(THREADS), 0, stream,
                       x, A1, A2, A3, A4, B1, B2, C1, C2, om, out);
}